// Round 3
// baseline (1227.259 us; speedup 1.0000x reference)
//
#include <hip/hip_runtime.h>
#include <hip/hip_fp16.h>
#include <hip/hip_bf16.h>

// Problem constants (from reference setup_inputs)
#define NC    32           // channels
#define NH1   256          // hidden dim
#define W_YX  727
#define H_YX  314
#define W_ZX  727
#define H_ZX  1300
#define W_ZY  314
#define H_ZY  1300
#define HW_YX (W_YX * H_YX)   // 228278
#define HW_ZX (W_ZX * H_ZX)   // 945100
#define HW_ZY (W_ZY * H_ZY)   // 408200

// merged prep-kernel block partition
#define NBW1  32                         // w1a: 8192 elems
#define NBW2  16                         // w2a: 4096 elems
#define NB_YX ((HW_YX + 255) / 256)      // 892
#define NB_ZX ((HW_ZX + 255) / 256)      // 3692
#define NB_ZY ((HW_ZY + 255) / 256)      // 1595
#define NB_HIST 1024                     // histogram blocks (grid-stride)
#define NB_PREP (NBW1 + NBW2 + NB_YX + NB_ZX + NB_ZY + NB_HIST)

// spatial sort: 16 z-groups x 32 x-bins = 512 bins
#define NXB   32
#define NZB   16
#define NBINS (NXB * NZB)

#define PSTRIDE 12         // dwords per point in parS  (12p%32: 2-way = free)
#define FSTRIDE 20         // dwords per point in featS (20p%32: 2-way, 16B-aligned)

typedef __attribute__((ext_vector_type(8))) short short8;   // 8 bf16 (4 VGPRs)
typedef __attribute__((ext_vector_type(4))) float f32x4;    // MFMA acc / io

// float -> bf16 (RNE), raw short (cold-path prep)
__device__ __forceinline__ short f2bf(float f) {
    unsigned u = __float_as_uint(f);
    unsigned r = u + 0x7fffu + ((u >> 16) & 1u);
    return (short)(r >> 16);
}
// pack two floats -> bf16 pair (RNE; v_cvt_pk_bf16_f32 on gfx950)
__device__ __forceinline__ unsigned pk2(float a, float b) {
    union { __hip_bfloat162 h; unsigned u; } c;
    c.h = __float22bfloat162_rn(make_float2(a, b));
    return c.u;
}

// spatial bin key: z-group (outer, 16) | x-bin (inner, 32).
// Localizes zx (bin patch), zy (z-slab), yx (x-slab) into per-XCD L2.
__device__ __forceinline__ int binkey(float px, float pz) {
    int xb = (int)((px + 1.0f) * 16.0f); xb = xb < 0 ? 0 : (xb > NXB - 1 ? NXB - 1 : xb);
    int zb = (int)((pz + 1.0f) * 8.0f);  zb = zb < 0 ? 0 : (zb > NZB - 1 ? NZB - 1 : zb);
    return zb * NXB + xb;
}

// ---------------------------------------------------------------------------
// Transpose body: (C=32, HW) fp32 -> (HW, C=32) bf16, 256 hw per block.
// ---------------------------------------------------------------------------
__device__ __forceinline__ void transpose_body(
    const float* __restrict__ src, unsigned short* __restrict__ dst,
    int HW, int hw0, int t)
{
    int c8 = t & 3;            // channel group (8 channels)
    int r  = t >> 2;           // 0..63: hw sub-tile
    int hwt = hw0 + r * 4;     // this thread's first hw

    if (hw0 + 256 <= HW) {
        f32x4 v[8];
#pragma unroll
        for (int cc = 0; cc < 8; ++cc) {
            int c = c8 * 8 + cc;
            v[cc] = *(const f32x4*)(src + (size_t)c * HW + hwt);
        }
#pragma unroll
        for (int k = 0; k < 4; ++k) {
            uint4 o;
            unsigned* ou = &o.x;
#pragma unroll
            for (int e = 0; e < 4; ++e)
                ou[e] = pk2(v[2 * e][k], v[2 * e + 1][k]);
            *(uint4*)(dst + (size_t)(hwt + k) * NC + c8 * 8) = o;
        }
    } else {
        for (int k = 0; k < 4; ++k) {
            int hw = hwt + k;
            if (hw < HW) {
                uint4 o;
                unsigned* ou = &o.x;
#pragma unroll
                for (int e = 0; e < 4; ++e) {
                    float a = src[(size_t)(c8 * 8 + 2 * e) * HW + hw];
                    float b = src[(size_t)(c8 * 8 + 2 * e + 1) * HW + hw];
                    ou[e] = pk2(a, b);
                }
                *(uint4*)(dst + (size_t)hw * NC + c8 * 8) = o;
            }
        }
    }
}

// ---------------------------------------------------------------------------
// ONE prep dispatch: w1a, w2a, 3 plane transposes, point-key histogram.
// ---------------------------------------------------------------------------
__global__ __launch_bounds__(256) void kplane_prep_all(
    const float* __restrict__ pyx, const float* __restrict__ pzx,
    const float* __restrict__ pzy,
    const float* __restrict__ w1, const float* __restrict__ w2,
    const float* __restrict__ pts, int N,
    unsigned short* __restrict__ tyx, unsigned short* __restrict__ tzx,
    unsigned short* __restrict__ tzy,
    short* __restrict__ w1a, short* __restrict__ w2a,
    unsigned* __restrict__ gHist)
{
    __shared__ unsigned lh[NBINS];
    int b = blockIdx.x;
    int t = threadIdx.x;

    if (b < NBW1) {                                 // ---- w1a ----
        int idx = b * 256 + t;                      // 0..8191
        int j    = idx & 7;
        int lane = (idx >> 3) & 63;
        int nt   = idx >> 9;
        int ch  = (lane >> 4) * 8 + j;
        int hid = nt * 16 + (lane & 15);
        w1a[idx] = f2bf(w1[ch * NH1 + hid]);
        return;
    }
    b -= NBW1;
    if (b < NBW2) {                                 // ---- w2a ----
        int idx = b * 256 + t;                      // 0..4095
        int j    = idx & 7;
        int lane = (idx >> 3) & 63;
        int kk   = idx >> 9;
        int o    = lane & 15;
        int quad = lane >> 4;
        int hid  = (2 * kk + (j >> 2)) * 16 + quad * 4 + (j & 3);
        float v  = (o < 4) ? w2[hid * 4 + o] : 0.0f;
        w2a[idx] = f2bf(v);
        return;
    }
    b -= NBW2;
    if (b < NB_YX + NB_ZX + NB_ZY) {                // ---- transposes ----
        const float* src; unsigned short* dst; int HW;
        if (b < NB_YX)              { src = pyx; dst = tyx; HW = HW_YX; }
        else if (b < NB_YX + NB_ZX) { b -= NB_YX; src = pzx; dst = tzx; HW = HW_ZX; }
        else                        { b -= NB_YX + NB_ZX; src = pzy; dst = tzy; HW = HW_ZY; }
        transpose_body(src, dst, HW, b * 256, t);
        return;
    }
    b -= NB_YX + NB_ZX + NB_ZY;                     // ---- histogram ----
    lh[t] = 0; lh[t + 256] = 0;
    __syncthreads();
    for (int i = b * 256 + t; i < N; i += NB_HIST * 256) {
        float px = pts[(size_t)i * 3 + 0];
        float pz = pts[(size_t)i * 3 + 2];
        atomicAdd(&lh[binkey(px, pz)], 1u);
    }
    __syncthreads();
    if (lh[t])       atomicAdd(&gHist[t], lh[t]);
    if (lh[t + 256]) atomicAdd(&gHist[t + 256], lh[t + 256]);
}

// ---------------------------------------------------------------------------
// Scan: exclusive prefix over 512 bin counts -> cursor (scatter bases) and
// gBase[17] (z-group point ranges for the fused kernel).
// ---------------------------------------------------------------------------
__global__ __launch_bounds__(256) void ksort_scan(
    const unsigned* __restrict__ gHist,
    unsigned* __restrict__ cursor, unsigned* __restrict__ gBase, int N)
{
    __shared__ unsigned h[NBINS], sup[64];
    int t = threadIdx.x;
    h[t] = gHist[t]; h[t + 256] = gHist[t + 256];
    __syncthreads();
    if (t < 64) {
        unsigned s = 0;
#pragma unroll
        for (int k = 0; k < 8; ++k) s += h[t * 8 + k];
        sup[t] = s;
    }
    __syncthreads();
    if (t == 0) {
        unsigned a = 0;
        for (int k = 0; k < 64; ++k) { unsigned v = sup[k]; sup[k] = a; a += v; }
    }
    __syncthreads();
    if (t < 64) {
        unsigned a = sup[t];
#pragma unroll
        for (int k = 0; k < 8; ++k) { unsigned v = h[t * 8 + k]; h[t * 8 + k] = a; a += v; }
    }
    __syncthreads();
    cursor[t] = h[t]; cursor[t + 256] = h[t + 256];
    if (t < NZB) gBase[t] = h[t * NXB];
    if (t == 0)  gBase[NZB] = (unsigned)N;
}

// ---------------------------------------------------------------------------
// Scatter: pts -> sorted float4 {x,y,z, bitcast(orig_idx)} in bin order.
// ---------------------------------------------------------------------------
__global__ __launch_bounds__(256) void ksort_scatter(
    const float* __restrict__ pts, int N,
    unsigned* __restrict__ cursor, float4* __restrict__ sp)
{
    for (int i = blockIdx.x * 256 + threadIdx.x; i < N; i += gridDim.x * 256) {
        float px = pts[(size_t)i * 3 + 0];
        float py = pts[(size_t)i * 3 + 1];
        float pz = pts[(size_t)i * 3 + 2];
        int key = binkey(px, pz);
        unsigned slot = atomicAdd(&cursor[key], 1u);
        float4 o; o.x = px; o.y = py; o.z = pz; o.w = __uint_as_float((unsigned)i);
        sp[slot] = o;
    }
}

// ---------------------------------------------------------------------------
// Bilinear setup: byte offsets of the two y-rows at x0 (x1 = +64B implicit;
// at the x-clamp edge wx==0 so the x1 half is weighted to zero).
// ---------------------------------------------------------------------------
__device__ __forceinline__ void bilin3(
    float gx, float gy, int W, int H,
    unsigned& o0, unsigned& o1, float& wx, float& wy)
{
    float ix  = (gx + 1.0f) * 0.5f * (float)(W - 1);
    float iy  = (gy + 1.0f) * 0.5f * (float)(H - 1);
    float x0f = floorf(ix), y0f = floorf(iy);
    wx = ix - x0f; wy = iy - y0f;
    int x0 = (int)x0f; x0 = x0 < 0 ? 0 : (x0 > W - 1 ? W - 1 : x0);
    int y0 = (int)y0f; y0 = y0 < 0 ? 0 : (y0 > H - 1 ? H - 1 : y0);
    int y1 = y0 + 1; if (y1 > H - 1) y1 = H - 1;
    o0 = (unsigned)(y0 * W + x0) * 64u;
    o1 = (unsigned)(y1 * W + x0) * 64u;
}

// Bilinear-combine 4 corner chunks (8 channels) fully in-lane.
template <bool FIRST>
__device__ __forceinline__ void corner4(
    const uint4& A, const uint4& B, const uint4& C, const uint4& D,
    float wx, float wy, float F[8])
{
    float w00 = (1.0f - wx) * (1.0f - wy);
    float w01 = wx * (1.0f - wy);
    float w10 = (1.0f - wx) * wy;
    float w11 = wx * wy;
    const unsigned* ua = &A.x; const unsigned* ub = &B.x;
    const unsigned* uc = &C.x; const unsigned* ud = &D.x;
#pragma unroll
    for (int e = 0; e < 4; ++e) {
        float a0 = __uint_as_float(ua[e] << 16);
        float a1 = __uint_as_float(ua[e] & 0xffff0000u);
        float b0 = __uint_as_float(ub[e] << 16);
        float b1 = __uint_as_float(ub[e] & 0xffff0000u);
        float c0 = __uint_as_float(uc[e] << 16);
        float c1 = __uint_as_float(uc[e] & 0xffff0000u);
        float d0 = __uint_as_float(ud[e] << 16);
        float d1 = __uint_as_float(ud[e] & 0xffff0000u);
        float v0 = w00 * a0; v0 = fmaf(w01, b0, v0);
        v0 = fmaf(w10, c0, v0); v0 = fmaf(w11, d0, v0);
        float v1 = w00 * a1; v1 = fmaf(w01, b1, v1);
        v1 = fmaf(w10, c1, v1); v1 = fmaf(w11, d1, v1);
        if (FIRST) { F[2 * e] = v0; F[2 * e + 1] = v1; }
        else       { F[2 * e] *= v0; F[2 * e + 1] *= v1; }
    }
}

// ---------------------------------------------------------------------------
// Fused kernel over SORTED points, XCD-pinned:
// block b -> xcd = b%8 -> z-groups {xcd, xcd+8}; chunks of 256 points.
// Phase 0: params + orig idx -> LDS.  Phase 1: gather (L2-local now).
// Phase 2: MFMA MLP, scatter-store to out[orig].
// ---------------------------------------------------------------------------
__global__ __launch_bounds__(256) void kplane_fused(
    const float4* __restrict__ sp, const unsigned* __restrict__ gBase, int cap,
    const unsigned short* __restrict__ tyx,
    const unsigned short* __restrict__ tzx,
    const unsigned short* __restrict__ tzy,
    const short* __restrict__ w1a, const short* __restrict__ w2a,
    const float* __restrict__ b1, const float* __restrict__ b2,
    float* __restrict__ out)
{
    __shared__ unsigned parS[256 * PSTRIDE];    // 12 KB
    __shared__ unsigned featS[256 * FSTRIDE];   // 20 KB
    __shared__ unsigned idxS[256];              // 1 KB

    int t = threadIdx.x;
    int bxcd = blockIdx.x & 7;
    int i    = blockIdx.x >> 3;
    int g    = bxcd + 8 * (i >= cap);
    int j    = (i >= cap) ? i - cap : i;
    unsigned gb = gBase[g], ge = gBase[g + 1];

    for (unsigned start = gb + (unsigned)j * 256u; start < ge;
         start += (unsigned)cap * 256u) {
        int npts = (int)(ge - start); if (npts > 256) npts = 256;
        __syncthreads();   // protect LDS reuse across chunks

        // ---- phase 0: bilinear params for point `t` -----------------------
        {
            uint4 P0 = {0,0,0,0}, P1 = {0,0,0,0}, P2 = {0,0,0,0};
            unsigned oid = 0xFFFFFFFFu;
            if (t < npts) {
                float4 p = sp[start + t];
                oid = __float_as_uint(p.w);
                unsigned a0, a1, c0, c1, d0, d1;
                float awx, awy, cwx, cwy, dwx, dwy;
                bilin3(p.x, p.y, W_YX, H_YX, a0, a1, awx, awy);
                bilin3(p.x, p.z, W_ZX, H_ZX, c0, c1, cwx, cwy);
                bilin3(p.y, p.z, W_ZY, H_ZY, d0, d1, dwx, dwy);
                P0 = {a0, a1, c0, c1};
                P1 = {d0, d1, __float_as_uint(awx), __float_as_uint(awy)};
                P2 = {__float_as_uint(cwx), __float_as_uint(cwy),
                      __float_as_uint(dwx), __float_as_uint(dwy)};
            }
            uint4* P = (uint4*)&parS[t * PSTRIDE];
            P[0] = P0; P[1] = P1; P[2] = P2;
            idxS[t] = oid;
        }
        __syncthreads();

        // ---- phase 1: gather, 4 lanes/point -------------------------------
        {
            int q = t >> 2, jj = t & 3;
            int jx16 = jj * 16;
            const char* Byx = (const char*)tyx;
            const char* Bzx = (const char*)tzx;
            const char* Bzy = (const char*)tzy;
#pragma unroll
            for (int r = 0; r < 4; ++r) {
                int p = r * 64 + q;
                const uint4* P = (const uint4*)&parS[p * PSTRIDE];
                uint4 P0 = P[0], P1 = P[1], P2 = P[2];
                float awx = __uint_as_float(P1.z), awy = __uint_as_float(P1.w);
                float cwx = __uint_as_float(P2.x), cwy = __uint_as_float(P2.y);
                float dwx = __uint_as_float(P2.z), dwy = __uint_as_float(P2.w);

                uint4 La = *(const uint4*)(Byx + P0.x + jx16);
                uint4 Lb = *(const uint4*)(Byx + P0.x + 64 + jx16);
                uint4 Lc = *(const uint4*)(Byx + P0.y + jx16);
                uint4 Ld = *(const uint4*)(Byx + P0.y + 64 + jx16);
                uint4 Ma = *(const uint4*)(Bzx + P0.z + jx16);
                uint4 Mb = *(const uint4*)(Bzx + P0.z + 64 + jx16);
                uint4 Mc = *(const uint4*)(Bzx + P0.w + jx16);
                uint4 Md = *(const uint4*)(Bzx + P0.w + 64 + jx16);
                uint4 Na = *(const uint4*)(Bzy + P1.x + jx16);
                uint4 Nb = *(const uint4*)(Bzy + P1.x + 64 + jx16);
                uint4 Nc = *(const uint4*)(Bzy + P1.y + jx16);
                uint4 Nd = *(const uint4*)(Bzy + P1.y + 64 + jx16);

                float F[8];
                corner4<true >(La, Lb, Lc, Ld, awx, awy, F);
                corner4<false>(Ma, Mb, Mc, Md, cwx, cwy, F);
                corner4<false>(Na, Nb, Nc, Nd, dwx, dwy, F);

                uint4 o;
                o.x = pk2(F[0], F[1]); o.y = pk2(F[2], F[3]);
                o.z = pk2(F[4], F[5]); o.w = pk2(F[6], F[7]);
                *(uint4*)&featS[p * FSTRIDE + jj * 4] = o;
            }
        }
        __syncthreads();

        // ---- phase 2: MFMA1 -> relu/pack -> MFMA2 -------------------------
        {
            int w = t >> 6, lane = t & 63;
            int quad = lane >> 4, l15 = lane & 15;
            const short8* W1A = (const short8*)w1a;
            const short8* W2A = (const short8*)w2a;
            const float4* B1v = (const float4*)b1;
            float b20 = b2[0], b21 = b2[1], b22 = b2[2], b23 = b2[3];

#pragma unroll
            for (int mt = 0; mt < 4; ++mt) {
                int pt = w * 64 + mt * 16 + l15;
                union { uint4 v; short8 s; } bf;
                bf.v = *(const uint4*)&featS[pt * FSTRIDE + quad * 4];

                f32x4 acc = {0.f, 0.f, 0.f, 0.f};
#pragma unroll
                for (int kk = 0; kk < 8; ++kk) {
                    float4 be = B1v[(2 * kk) * 4 + quad];
                    float4 bo = B1v[(2 * kk + 1) * 4 + quad];
                    f32x4 ze = {be.x, be.y, be.z, be.w};
                    f32x4 zo = {bo.x, bo.y, bo.z, bo.w};
                    ze = __builtin_amdgcn_mfma_f32_16x16x32_bf16(
                             W1A[(2 * kk) * 64 + lane], bf.s, ze, 0, 0, 0);
                    zo = __builtin_amdgcn_mfma_f32_16x16x32_bf16(
                             W1A[(2 * kk + 1) * 64 + lane], bf.s, zo, 0, 0, 0);
                    union { unsigned u[4]; short8 s; } hb;
                    hb.u[0] = pk2(fmaxf(ze[0], 0.f), fmaxf(ze[1], 0.f));
                    hb.u[1] = pk2(fmaxf(ze[2], 0.f), fmaxf(ze[3], 0.f));
                    hb.u[2] = pk2(fmaxf(zo[0], 0.f), fmaxf(zo[1], 0.f));
                    hb.u[3] = pk2(fmaxf(zo[2], 0.f), fmaxf(zo[3], 0.f));
                    acc = __builtin_amdgcn_mfma_f32_16x16x32_bf16(
                              W2A[kk * 64 + lane], hb.s, acc, 0, 0, 0);
                }
                unsigned orig = idxS[pt];
                if (quad == 0 && orig != 0xFFFFFFFFu) {
                    f32x4 o = {acc[0] + b20, acc[1] + b21, acc[2] + b22, acc[3] + b23};
                    *((f32x4*)out + orig) = o;
                }
            }
        }
    }
}

// ---------------------------------------------------------------------------
// Fallback path (ws too small): direct (C,H,W) gather, VALU MLP.
// ---------------------------------------------------------------------------
__device__ __forceinline__ void bilin_full(
    float gx, float gy, int W, int H,
    int& o00, int& o01, int& o10, int& o11,
    float& w00, float& w01, float& w10, float& w11)
{
    float ix  = (gx + 1.0f) * 0.5f * (float)(W - 1);
    float iy  = (gy + 1.0f) * 0.5f * (float)(H - 1);
    float x0f = floorf(ix), y0f = floorf(iy);
    float wx  = ix - x0f,   wy  = iy - y0f;
    int x0 = (int)x0f; x0 = x0 < 0 ? 0 : (x0 > W - 1 ? W - 1 : x0);
    int y0 = (int)y0f; y0 = y0 < 0 ? 0 : (y0 > H - 1 ? H - 1 : y0);
    int x1 = x0 + 1; if (x1 > W - 1) x1 = W - 1;
    int y1 = y0 + 1; if (y1 > H - 1) y1 = H - 1;
    o00 = y0 * W + x0; o01 = y0 * W + x1;
    o10 = y1 * W + x0; o11 = y1 * W + x1;
    w00 = (1.0f - wx) * (1.0f - wy);
    w01 = wx * (1.0f - wy);
    w10 = (1.0f - wx) * wy;
    w11 = wx * wy;
}

__global__ __launch_bounds__(256) void kplane_fused_direct(
    const float* __restrict__ pts,
    const float* __restrict__ pyx, const float* __restrict__ pzx,
    const float* __restrict__ pzy,
    const float* __restrict__ w1, const float* __restrict__ b1,
    const float* __restrict__ w2, const float* __restrict__ b2,
    float* __restrict__ out, int N)
{
    int i = blockIdx.x * blockDim.x + threadIdx.x;
    if (i >= N) return;
    float px = pts[(size_t)i * 3 + 0];
    float py = pts[(size_t)i * 3 + 1];
    float pz = pts[(size_t)i * 3 + 2];

    int a00, a01, a10, a11; float aw00, aw01, aw10, aw11;
    int c00, c01, c10, c11; float cw00, cw01, cw10, cw11;
    int d00, d01, d10, d11; float dw00, dw01, dw10, dw11;
    bilin_full(px, py, W_YX, H_YX, a00, a01, a10, a11, aw00, aw01, aw10, aw11);
    bilin_full(px, pz, W_ZX, H_ZX, c00, c01, c10, c11, cw00, cw01, cw10, cw11);
    bilin_full(py, pz, W_ZY, H_ZY, d00, d01, d10, d11, dw00, dw01, dw10, dw11);

    float feat[NC];
#pragma unroll 4
    for (int c = 0; c < NC; ++c) {
        const float* byx = pyx + (size_t)c * HW_YX;
        const float* bzx = pzx + (size_t)c * HW_ZX;
        const float* bzy = pzy + (size_t)c * HW_ZY;
        float fyx = aw00 * byx[a00] + aw01 * byx[a01] + aw10 * byx[a10] + aw11 * byx[a11];
        float fzx = cw00 * bzx[c00] + cw01 * bzx[c01] + cw10 * bzx[c10] + cw11 * bzx[c11];
        float fzy = dw00 * bzy[d00] + dw01 * bzy[d01] + dw10 * bzy[d10] + dw11 * bzy[d11];
        feat[c] = fyx * fzx * fzy;
    }
    float o0 = b2[0], o1 = b2[1], o2 = b2[2], o3 = b2[3];
#pragma unroll 4
    for (int k = 0; k < NH1; ++k) {
        float hk = b1[k];
#pragma unroll
        for (int c = 0; c < NC; ++c)
            hk = fmaf(feat[c], w1[c * NH1 + k], hk);
        hk = fmaxf(hk, 0.0f);
        o0 = fmaf(hk, w2[k * 4 + 0], o0);
        o1 = fmaf(hk, w2[k * 4 + 1], o1);
        o2 = fmaf(hk, w2[k * 4 + 2], o2);
        o3 = fmaf(hk, w2[k * 4 + 3], o3);
    }
    float4 o; o.x = o0; o.y = o1; o.z = o2; o.w = o3;
    reinterpret_cast<float4*>(out)[i] = o;
}

// ---------------------------------------------------------------------------
extern "C" void kernel_launch(void* const* d_in, const int* in_sizes, int n_in,
                              void* d_out, int out_size, void* d_ws, size_t ws_size,
                              hipStream_t stream)
{
    const float* pts = (const float*)d_in[0];
    const float* pyx = (const float*)d_in[1];
    const float* pzx = (const float*)d_in[2];
    const float* pzy = (const float*)d_in[3];
    const float* w1  = (const float*)d_in[4];
    const float* b1  = (const float*)d_in[5];
    const float* w2  = (const float*)d_in[6];
    const float* b2  = (const float*)d_in[7];
    float* out = (float*)d_out;

    int N = in_sizes[0] / 3;

    size_t planes_b = (size_t)(HW_YX + HW_ZX + HW_ZY) * NC * sizeof(short); // bf16 planes
    size_t frag_b   = (8192 + 4096) * sizeof(short);
    size_t sort_b   = (size_t)N * 16;
    size_t meta_b   = (NBINS + NBINS + 32) * sizeof(unsigned);
    size_t need     = planes_b + frag_b + sort_b + meta_b + 256;

    if (ws_size >= need) {
        unsigned short* tyx = (unsigned short*)d_ws;
        unsigned short* tzx = tyx + (size_t)HW_YX * NC;
        unsigned short* tzy = tzx + (size_t)HW_ZX * NC;
        short* w1a = (short*)(tzy + (size_t)HW_ZY * NC);
        short* w2a = w1a + 8192;
        float4* sorted = (float4*)(w2a + 4096);
        unsigned* gHist  = (unsigned*)(sorted + N);
        unsigned* cursor = gHist + NBINS;
        unsigned* gBase  = cursor + NBINS;

        hipMemsetAsync(gHist, 0, NBINS * sizeof(unsigned), stream);
        kplane_prep_all<<<NB_PREP, 256, 0, stream>>>(pyx, pzx, pzy, w1, w2,
                                                     pts, N, tyx, tzx, tzy,
                                                     w1a, w2a, gHist);
        ksort_scan<<<1, 256, 0, stream>>>(gHist, cursor, gBase, N);
        ksort_scatter<<<2048, 256, 0, stream>>>(pts, N, cursor, sorted);

        // per-z-group chunk capacity (uniform + 25% slack; while-loop covers rest)
        int cap = (N / NZB + N / (NZB * 4)) / 256 + 2;
        kplane_fused<<<16 * cap, 256, 0, stream>>>(sorted, gBase, cap,
                                                   tyx, tzx, tzy,
                                                   w1a, w2a, b1, b2, out);
    } else {
        int blocks = (N + 255) / 256;
        kplane_fused_direct<<<blocks, 256, 0, stream>>>(pts, pyx, pzx, pzy,
                                                        w1, b1, w2, b2, out, N);
    }
}

// Round 4
// 632.275 us; speedup vs baseline: 1.9410x; 1.9410x over previous
//
#include <hip/hip_runtime.h>
#include <hip/hip_fp16.h>
#include <hip/hip_bf16.h>

// Problem constants (from reference setup_inputs)
#define NC    32           // channels
#define NH1   256          // hidden dim
#define W_YX  727
#define H_YX  314
#define W_ZX  727
#define H_ZX  1300
#define W_ZY  314
#define H_ZY  1300
#define HW_YX (W_YX * H_YX)   // 228278
#define HW_ZX (W_ZX * H_ZX)   // 945100
#define HW_ZY (W_ZY * H_ZY)   // 408200

// spatial sort: 16 z-groups x 32 x-bins = 512 bins
#define NXB   32
#define NZB   16
#define NBINS (NXB * NZB)
#define NB_SCAT 512                      // scatter chunks (deterministic sort)

// merged prep-kernel block partition
#define NBW1  32                         // w1a: 8192 elems
#define NBW2  16                         // w2a: 4096 elems
#define NB_YX ((HW_YX + 255) / 256)      // 892
#define NB_ZX ((HW_ZX + 255) / 256)      // 3692
#define NB_ZY ((HW_ZY + 255) / 256)      // 1595
#define NB_PREP (NBW1 + NBW2 + NB_YX + NB_ZX + NB_ZY + NB_SCAT)

#define PSTRIDE 12         // dwords per point in parS  (12p%32: 2-way = free)
#define FSTRIDE 20         // dwords per point in featS (20p%32: 2-way, 16B-aligned)

typedef __attribute__((ext_vector_type(8))) short short8;   // 8 bf16 (4 VGPRs)
typedef __attribute__((ext_vector_type(4))) float f32x4;    // MFMA acc / io

// float -> bf16 (RNE), raw short (cold-path prep)
__device__ __forceinline__ short f2bf(float f) {
    unsigned u = __float_as_uint(f);
    unsigned r = u + 0x7fffu + ((u >> 16) & 1u);
    return (short)(r >> 16);
}
// pack two floats -> bf16 pair (RNE; v_cvt_pk_bf16_f32 on gfx950)
__device__ __forceinline__ unsigned pk2(float a, float b) {
    union { __hip_bfloat162 h; unsigned u; } c;
    c.h = __float22bfloat162_rn(make_float2(a, b));
    return c.u;
}

// spatial bin key: z-group (outer, 16) | x-bin (inner, 32).
// Localizes zx (bin patch), zy (z-slab), yx (x-slab) into per-XCD L2.
__device__ __forceinline__ int binkey(float px, float pz) {
    int xb = (int)((px + 1.0f) * 16.0f); xb = xb < 0 ? 0 : (xb > NXB - 1 ? NXB - 1 : xb);
    int zb = (int)((pz + 1.0f) * 8.0f);  zb = zb < 0 ? 0 : (zb > NZB - 1 ? NZB - 1 : zb);
    return zb * NXB + xb;
}

// ---------------------------------------------------------------------------
// Transpose body: (C=32, HW) fp32 -> (HW, C=32) bf16, 256 hw per block.
// ---------------------------------------------------------------------------
__device__ __forceinline__ void transpose_body(
    const float* __restrict__ src, unsigned short* __restrict__ dst,
    int HW, int hw0, int t)
{
    int c8 = t & 3;            // channel group (8 channels)
    int r  = t >> 2;           // 0..63: hw sub-tile
    int hwt = hw0 + r * 4;     // this thread's first hw

    if (hw0 + 256 <= HW) {
        f32x4 v[8];
#pragma unroll
        for (int cc = 0; cc < 8; ++cc) {
            int c = c8 * 8 + cc;
            v[cc] = *(const f32x4*)(src + (size_t)c * HW + hwt);
        }
#pragma unroll
        for (int k = 0; k < 4; ++k) {
            uint4 o;
            unsigned* ou = &o.x;
#pragma unroll
            for (int e = 0; e < 4; ++e)
                ou[e] = pk2(v[2 * e][k], v[2 * e + 1][k]);
            *(uint4*)(dst + (size_t)(hwt + k) * NC + c8 * 8) = o;
        }
    } else {
        for (int k = 0; k < 4; ++k) {
            int hw = hwt + k;
            if (hw < HW) {
                uint4 o;
                unsigned* ou = &o.x;
#pragma unroll
                for (int e = 0; e < 4; ++e) {
                    float a = src[(size_t)(c8 * 8 + 2 * e) * HW + hw];
                    float b = src[(size_t)(c8 * 8 + 2 * e + 1) * HW + hw];
                    ou[e] = pk2(a, b);
                }
                *(uint4*)(dst + (size_t)hw * NC + c8 * 8) = o;
            }
        }
    }
}

// ---------------------------------------------------------------------------
// ONE prep dispatch: w1a, w2a, 3 plane transposes, per-chunk histograms.
// Chunk h = points [h*chunk, (h+1)*chunk); bh[bin*NB_SCAT + h] = count.
// No global atomics anywhere.
// ---------------------------------------------------------------------------
__global__ __launch_bounds__(256) void kplane_prep_all(
    const float* __restrict__ pyx, const float* __restrict__ pzx,
    const float* __restrict__ pzy,
    const float* __restrict__ w1, const float* __restrict__ w2,
    const float* __restrict__ pts, int N, int chunk,
    unsigned short* __restrict__ tyx, unsigned short* __restrict__ tzx,
    unsigned short* __restrict__ tzy,
    short* __restrict__ w1a, short* __restrict__ w2a,
    unsigned* __restrict__ bh)
{
    __shared__ unsigned lh[NBINS];
    int b = blockIdx.x;
    int t = threadIdx.x;

    if (b < NBW1) {                                 // ---- w1a ----
        int idx = b * 256 + t;                      // 0..8191
        int j    = idx & 7;
        int lane = (idx >> 3) & 63;
        int nt   = idx >> 9;
        int ch  = (lane >> 4) * 8 + j;
        int hid = nt * 16 + (lane & 15);
        w1a[idx] = f2bf(w1[ch * NH1 + hid]);
        return;
    }
    b -= NBW1;
    if (b < NBW2) {                                 // ---- w2a ----
        int idx = b * 256 + t;                      // 0..4095
        int j    = idx & 7;
        int lane = (idx >> 3) & 63;
        int kk   = idx >> 9;
        int o    = lane & 15;
        int quad = lane >> 4;
        int hid  = (2 * kk + (j >> 2)) * 16 + quad * 4 + (j & 3);
        float v  = (o < 4) ? w2[hid * 4 + o] : 0.0f;
        w2a[idx] = f2bf(v);
        return;
    }
    b -= NBW2;
    if (b < NB_YX + NB_ZX + NB_ZY) {                // ---- transposes ----
        const float* src; unsigned short* dst; int HW;
        if (b < NB_YX)              { src = pyx; dst = tyx; HW = HW_YX; }
        else if (b < NB_YX + NB_ZX) { b -= NB_YX; src = pzx; dst = tzx; HW = HW_ZX; }
        else                        { b -= NB_YX + NB_ZX; src = pzy; dst = tzy; HW = HW_ZY; }
        transpose_body(src, dst, HW, b * 256, t);
        return;
    }
    b -= NB_YX + NB_ZX + NB_ZY;                     // ---- chunk histogram ----
    lh[t] = 0; lh[t + 256] = 0;
    __syncthreads();
    long i0 = (long)b * chunk;
    for (int k = 0; k < chunk; k += 256) {
        long i = i0 + k + t;
        if (i < N) {
            float px = pts[i * 3 + 0];
            float pz = pts[i * 3 + 2];
            atomicAdd(&lh[binkey(px, pz)], 1u);     // LDS atomic only
        }
    }
    __syncthreads();
    bh[(size_t)t * NB_SCAT + b]         = lh[t];
    bh[(size_t)(t + 256) * NB_SCAT + b] = lh[t + 256];
}

// ---------------------------------------------------------------------------
// Scan A: per bin, exclusive scan over the NB_SCAT chunk counts (in place);
// binTotal[bin] = sum. One block per bin.
// ---------------------------------------------------------------------------
__global__ __launch_bounds__(256) void ksort_scanA(
    unsigned* __restrict__ bh, unsigned* __restrict__ binTotal)
{
    __shared__ unsigned s[NB_SCAT];
    int b = blockIdx.x, t = threadIdx.x;
    s[t]       = bh[(size_t)b * NB_SCAT + t];
    s[t + 256] = bh[(size_t)b * NB_SCAT + 256 + t];
    __syncthreads();
    if (t == 0) {
        unsigned a = 0;
        for (int k = 0; k < NB_SCAT; ++k) { unsigned v = s[k]; s[k] = a; a += v; }
        binTotal[b] = a;
    }
    __syncthreads();
    bh[(size_t)b * NB_SCAT + t]       = s[t];
    bh[(size_t)b * NB_SCAT + 256 + t] = s[t + 256];
}

// ---------------------------------------------------------------------------
// Scan B: exclusive scan over 512 bin totals -> binBase; z-group ranges.
// ---------------------------------------------------------------------------
__global__ __launch_bounds__(256) void ksort_scanB(
    const unsigned* __restrict__ binTotal, unsigned* __restrict__ binBase,
    unsigned* __restrict__ gBase, int N)
{
    __shared__ unsigned s[NBINS];
    int t = threadIdx.x;
    s[t] = binTotal[t]; s[t + 256] = binTotal[t + 256];
    __syncthreads();
    if (t == 0) {
        unsigned a = 0;
        for (int k = 0; k < NBINS; ++k) { unsigned v = s[k]; s[k] = a; a += v; }
    }
    __syncthreads();
    binBase[t] = s[t]; binBase[t + 256] = s[t + 256];
    if (t < NZB) gBase[t] = s[t * NXB];
    if (t == 0)  gBase[NZB] = (unsigned)N;
}

// ---------------------------------------------------------------------------
// Scatter: block h re-reads its chunk, ranks points per bin via LDS counters,
// writes to exact slot binBase[key] + bh[key][h] + rank. Zero global atomics;
// per-(block,bin) output runs are contiguous -> low write amplification.
// ---------------------------------------------------------------------------
__global__ __launch_bounds__(256) void ksort_scatter(
    const float* __restrict__ pts, int N, int chunk,
    const unsigned* __restrict__ bh, const unsigned* __restrict__ binBase,
    float4* __restrict__ sp)
{
    __shared__ unsigned cnt[NBINS];
    __shared__ unsigned baseS[NBINS];
    int h = blockIdx.x, t = threadIdx.x;
    cnt[t] = 0; cnt[t + 256] = 0;
    baseS[t]       = binBase[t]       + bh[(size_t)t * NB_SCAT + h];
    baseS[t + 256] = binBase[t + 256] + bh[(size_t)(t + 256) * NB_SCAT + h];
    __syncthreads();
    long i0 = (long)h * chunk;
    for (int k = 0; k < chunk; k += 256) {
        long i = i0 + k + t;
        if (i < N) {
            float px = pts[i * 3 + 0];
            float py = pts[i * 3 + 1];
            float pz = pts[i * 3 + 2];
            int key = binkey(px, pz);
            unsigned rank = atomicAdd(&cnt[key], 1u);   // LDS atomic only
            float4 o; o.x = px; o.y = py; o.z = pz;
            o.w = __uint_as_float((unsigned)i);
            sp[baseS[key] + rank] = o;
        }
    }
}

// ---------------------------------------------------------------------------
// Bilinear setup: byte offsets of the two y-rows at x0 (x1 = +64B implicit;
// at the x-clamp edge wx==0 so the x1 half is weighted to zero).
// ---------------------------------------------------------------------------
__device__ __forceinline__ void bilin3(
    float gx, float gy, int W, int H,
    unsigned& o0, unsigned& o1, float& wx, float& wy)
{
    float ix  = (gx + 1.0f) * 0.5f * (float)(W - 1);
    float iy  = (gy + 1.0f) * 0.5f * (float)(H - 1);
    float x0f = floorf(ix), y0f = floorf(iy);
    wx = ix - x0f; wy = iy - y0f;
    int x0 = (int)x0f; x0 = x0 < 0 ? 0 : (x0 > W - 1 ? W - 1 : x0);
    int y0 = (int)y0f; y0 = y0 < 0 ? 0 : (y0 > H - 1 ? H - 1 : y0);
    int y1 = y0 + 1; if (y1 > H - 1) y1 = H - 1;
    o0 = (unsigned)(y0 * W + x0) * 64u;
    o1 = (unsigned)(y1 * W + x0) * 64u;
}

// Bilinear-combine 4 corner chunks (8 channels) fully in-lane.
template <bool FIRST>
__device__ __forceinline__ void corner4(
    const uint4& A, const uint4& B, const uint4& C, const uint4& D,
    float wx, float wy, float F[8])
{
    float w00 = (1.0f - wx) * (1.0f - wy);
    float w01 = wx * (1.0f - wy);
    float w10 = (1.0f - wx) * wy;
    float w11 = wx * wy;
    const unsigned* ua = &A.x; const unsigned* ub = &B.x;
    const unsigned* uc = &C.x; const unsigned* ud = &D.x;
#pragma unroll
    for (int e = 0; e < 4; ++e) {
        float a0 = __uint_as_float(ua[e] << 16);
        float a1 = __uint_as_float(ua[e] & 0xffff0000u);
        float b0 = __uint_as_float(ub[e] << 16);
        float b1 = __uint_as_float(ub[e] & 0xffff0000u);
        float c0 = __uint_as_float(uc[e] << 16);
        float c1 = __uint_as_float(uc[e] & 0xffff0000u);
        float d0 = __uint_as_float(ud[e] << 16);
        float d1 = __uint_as_float(ud[e] & 0xffff0000u);
        float v0 = w00 * a0; v0 = fmaf(w01, b0, v0);
        v0 = fmaf(w10, c0, v0); v0 = fmaf(w11, d0, v0);
        float v1 = w00 * a1; v1 = fmaf(w01, b1, v1);
        v1 = fmaf(w10, c1, v1); v1 = fmaf(w11, d1, v1);
        if (FIRST) { F[2 * e] = v0; F[2 * e + 1] = v1; }
        else       { F[2 * e] *= v0; F[2 * e + 1] *= v1; }
    }
}

// ---------------------------------------------------------------------------
// Fused kernel over SORTED points, XCD-pinned:
// block b -> xcd = b%8 -> z-groups {xcd, xcd+8}; chunks of 256 points.
// ---------------------------------------------------------------------------
__global__ __launch_bounds__(256) void kplane_fused(
    const float4* __restrict__ sp, const unsigned* __restrict__ gBase, int cap,
    const unsigned short* __restrict__ tyx,
    const unsigned short* __restrict__ tzx,
    const unsigned short* __restrict__ tzy,
    const short* __restrict__ w1a, const short* __restrict__ w2a,
    const float* __restrict__ b1, const float* __restrict__ b2,
    float* __restrict__ out)
{
    __shared__ unsigned parS[256 * PSTRIDE];    // 12 KB
    __shared__ unsigned featS[256 * FSTRIDE];   // 20 KB
    __shared__ unsigned idxS[256];              // 1 KB

    int t = threadIdx.x;
    int bxcd = blockIdx.x & 7;
    int i    = blockIdx.x >> 3;
    int g    = bxcd + 8 * (i >= cap);
    int j    = (i >= cap) ? i - cap : i;
    unsigned gb = gBase[g], ge = gBase[g + 1];

    for (unsigned start = gb + (unsigned)j * 256u; start < ge;
         start += (unsigned)cap * 256u) {
        int npts = (int)(ge - start); if (npts > 256) npts = 256;
        __syncthreads();   // protect LDS reuse across chunks

        // ---- phase 0: bilinear params for point `t` -----------------------
        {
            uint4 P0 = {0,0,0,0}, P1 = {0,0,0,0}, P2 = {0,0,0,0};
            unsigned oid = 0xFFFFFFFFu;
            if (t < npts) {
                float4 p = sp[start + t];
                oid = __float_as_uint(p.w);
                unsigned a0, a1, c0, c1, d0, d1;
                float awx, awy, cwx, cwy, dwx, dwy;
                bilin3(p.x, p.y, W_YX, H_YX, a0, a1, awx, awy);
                bilin3(p.x, p.z, W_ZX, H_ZX, c0, c1, cwx, cwy);
                bilin3(p.y, p.z, W_ZY, H_ZY, d0, d1, dwx, dwy);
                P0 = {a0, a1, c0, c1};
                P1 = {d0, d1, __float_as_uint(awx), __float_as_uint(awy)};
                P2 = {__float_as_uint(cwx), __float_as_uint(cwy),
                      __float_as_uint(dwx), __float_as_uint(dwy)};
            }
            uint4* P = (uint4*)&parS[t * PSTRIDE];
            P[0] = P0; P[1] = P1; P[2] = P2;
            idxS[t] = oid;
        }
        __syncthreads();

        // ---- phase 1: gather, 4 lanes/point -------------------------------
        {
            int q = t >> 2, jj = t & 3;
            int jx16 = jj * 16;
            const char* Byx = (const char*)tyx;
            const char* Bzx = (const char*)tzx;
            const char* Bzy = (const char*)tzy;
#pragma unroll
            for (int r = 0; r < 4; ++r) {
                int p = r * 64 + q;
                const uint4* P = (const uint4*)&parS[p * PSTRIDE];
                uint4 P0 = P[0], P1 = P[1], P2 = P[2];
                float awx = __uint_as_float(P1.z), awy = __uint_as_float(P1.w);
                float cwx = __uint_as_float(P2.x), cwy = __uint_as_float(P2.y);
                float dwx = __uint_as_float(P2.z), dwy = __uint_as_float(P2.w);

                uint4 La = *(const uint4*)(Byx + P0.x + jx16);
                uint4 Lb = *(const uint4*)(Byx + P0.x + 64 + jx16);
                uint4 Lc = *(const uint4*)(Byx + P0.y + jx16);
                uint4 Ld = *(const uint4*)(Byx + P0.y + 64 + jx16);
                uint4 Ma = *(const uint4*)(Bzx + P0.z + jx16);
                uint4 Mb = *(const uint4*)(Bzx + P0.z + 64 + jx16);
                uint4 Mc = *(const uint4*)(Bzx + P0.w + jx16);
                uint4 Md = *(const uint4*)(Bzx + P0.w + 64 + jx16);
                uint4 Na = *(const uint4*)(Bzy + P1.x + jx16);
                uint4 Nb = *(const uint4*)(Bzy + P1.x + 64 + jx16);
                uint4 Nc = *(const uint4*)(Bzy + P1.y + jx16);
                uint4 Nd = *(const uint4*)(Bzy + P1.y + 64 + jx16);

                float F[8];
                corner4<true >(La, Lb, Lc, Ld, awx, awy, F);
                corner4<false>(Ma, Mb, Mc, Md, cwx, cwy, F);
                corner4<false>(Na, Nb, Nc, Nd, dwx, dwy, F);

                uint4 o;
                o.x = pk2(F[0], F[1]); o.y = pk2(F[2], F[3]);
                o.z = pk2(F[4], F[5]); o.w = pk2(F[6], F[7]);
                *(uint4*)&featS[p * FSTRIDE + jj * 4] = o;
            }
        }
        __syncthreads();

        // ---- phase 2: MFMA1 -> relu/pack -> MFMA2 -------------------------
        {
            int w = t >> 6, lane = t & 63;
            int quad = lane >> 4, l15 = lane & 15;
            const short8* W1A = (const short8*)w1a;
            const short8* W2A = (const short8*)w2a;
            const float4* B1v = (const float4*)b1;
            float b20 = b2[0], b21 = b2[1], b22 = b2[2], b23 = b2[3];

#pragma unroll
            for (int mt = 0; mt < 4; ++mt) {
                int pt = w * 64 + mt * 16 + l15;
                union { uint4 v; short8 s; } bf;
                bf.v = *(const uint4*)&featS[pt * FSTRIDE + quad * 4];

                f32x4 acc = {0.f, 0.f, 0.f, 0.f};
#pragma unroll
                for (int kk = 0; kk < 8; ++kk) {
                    float4 be = B1v[(2 * kk) * 4 + quad];
                    float4 bo = B1v[(2 * kk + 1) * 4 + quad];
                    f32x4 ze = {be.x, be.y, be.z, be.w};
                    f32x4 zo = {bo.x, bo.y, bo.z, bo.w};
                    ze = __builtin_amdgcn_mfma_f32_16x16x32_bf16(
                             W1A[(2 * kk) * 64 + lane], bf.s, ze, 0, 0, 0);
                    zo = __builtin_amdgcn_mfma_f32_16x16x32_bf16(
                             W1A[(2 * kk + 1) * 64 + lane], bf.s, zo, 0, 0, 0);
                    union { unsigned u[4]; short8 s; } hb;
                    hb.u[0] = pk2(fmaxf(ze[0], 0.f), fmaxf(ze[1], 0.f));
                    hb.u[1] = pk2(fmaxf(ze[2], 0.f), fmaxf(ze[3], 0.f));
                    hb.u[2] = pk2(fmaxf(zo[0], 0.f), fmaxf(zo[1], 0.f));
                    hb.u[3] = pk2(fmaxf(zo[2], 0.f), fmaxf(zo[3], 0.f));
                    acc = __builtin_amdgcn_mfma_f32_16x16x32_bf16(
                              W2A[kk * 64 + lane], hb.s, acc, 0, 0, 0);
                }
                unsigned orig = idxS[pt];
                if (quad == 0 && orig != 0xFFFFFFFFu) {
                    f32x4 o = {acc[0] + b20, acc[1] + b21, acc[2] + b22, acc[3] + b23};
                    *((f32x4*)out + orig) = o;
                }
            }
        }
    }
}

// ---------------------------------------------------------------------------
// Fallback path (ws too small): direct (C,H,W) gather, VALU MLP.
// ---------------------------------------------------------------------------
__device__ __forceinline__ void bilin_full(
    float gx, float gy, int W, int H,
    int& o00, int& o01, int& o10, int& o11,
    float& w00, float& w01, float& w10, float& w11)
{
    float ix  = (gx + 1.0f) * 0.5f * (float)(W - 1);
    float iy  = (gy + 1.0f) * 0.5f * (float)(H - 1);
    float x0f = floorf(ix), y0f = floorf(iy);
    float wx  = ix - x0f,   wy  = iy - y0f;
    int x0 = (int)x0f; x0 = x0 < 0 ? 0 : (x0 > W - 1 ? W - 1 : x0);
    int y0 = (int)y0f; y0 = y0 < 0 ? 0 : (y0 > H - 1 ? H - 1 : y0);
    int x1 = x0 + 1; if (x1 > W - 1) x1 = W - 1;
    int y1 = y0 + 1; if (y1 > H - 1) y1 = H - 1;
    o00 = y0 * W + x0; o01 = y0 * W + x1;
    o10 = y1 * W + x0; o11 = y1 * W + x1;
    w00 = (1.0f - wx) * (1.0f - wy);
    w01 = wx * (1.0f - wy);
    w10 = (1.0f - wx) * wy;
    w11 = wx * wy;
}

__global__ __launch_bounds__(256) void kplane_fused_direct(
    const float* __restrict__ pts,
    const float* __restrict__ pyx, const float* __restrict__ pzx,
    const float* __restrict__ pzy,
    const float* __restrict__ w1, const float* __restrict__ b1,
    const float* __restrict__ w2, const float* __restrict__ b2,
    float* __restrict__ out, int N)
{
    int i = blockIdx.x * blockDim.x + threadIdx.x;
    if (i >= N) return;
    float px = pts[(size_t)i * 3 + 0];
    float py = pts[(size_t)i * 3 + 1];
    float pz = pts[(size_t)i * 3 + 2];

    int a00, a01, a10, a11; float aw00, aw01, aw10, aw11;
    int c00, c01, c10, c11; float cw00, cw01, cw10, cw11;
    int d00, d01, d10, d11; float dw00, dw01, dw10, dw11;
    bilin_full(px, py, W_YX, H_YX, a00, a01, a10, a11, aw00, aw01, aw10, aw11);
    bilin_full(px, pz, W_ZX, H_ZX, c00, c01, c10, c11, cw00, cw01, cw10, cw11);
    bilin_full(py, pz, W_ZY, H_ZY, d00, d01, d10, d11, dw00, dw01, dw10, dw11);

    float feat[NC];
#pragma unroll 4
    for (int c = 0; c < NC; ++c) {
        const float* byx = pyx + (size_t)c * HW_YX;
        const float* bzx = pzx + (size_t)c * HW_ZX;
        const float* bzy = pzy + (size_t)c * HW_ZY;
        float fyx = aw00 * byx[a00] + aw01 * byx[a01] + aw10 * byx[a10] + aw11 * byx[a11];
        float fzx = cw00 * bzx[c00] + cw01 * bzx[c01] + cw10 * bzx[c10] + cw11 * bzx[c11];
        float fzy = dw00 * bzy[d00] + dw01 * bzy[d01] + dw10 * bzy[d10] + dw11 * bzy[d11];
        feat[c] = fyx * fzx * fzy;
    }
    float o0 = b2[0], o1 = b2[1], o2 = b2[2], o3 = b2[3];
#pragma unroll 4
    for (int k = 0; k < NH1; ++k) {
        float hk = b1[k];
#pragma unroll
        for (int c = 0; c < NC; ++c)
            hk = fmaf(feat[c], w1[c * NH1 + k], hk);
        hk = fmaxf(hk, 0.0f);
        o0 = fmaf(hk, w2[k * 4 + 0], o0);
        o1 = fmaf(hk, w2[k * 4 + 1], o1);
        o2 = fmaf(hk, w2[k * 4 + 2], o2);
        o3 = fmaf(hk, w2[k * 4 + 3], o3);
    }
    float4 o; o.x = o0; o.y = o1; o.z = o2; o.w = o3;
    reinterpret_cast<float4*>(out)[i] = o;
}

// ---------------------------------------------------------------------------
extern "C" void kernel_launch(void* const* d_in, const int* in_sizes, int n_in,
                              void* d_out, int out_size, void* d_ws, size_t ws_size,
                              hipStream_t stream)
{
    const float* pts = (const float*)d_in[0];
    const float* pyx = (const float*)d_in[1];
    const float* pzx = (const float*)d_in[2];
    const float* pzy = (const float*)d_in[3];
    const float* w1  = (const float*)d_in[4];
    const float* b1  = (const float*)d_in[5];
    const float* w2  = (const float*)d_in[6];
    const float* b2  = (const float*)d_in[7];
    float* out = (float*)d_out;

    int N = in_sizes[0] / 3;

    size_t planes_b = (size_t)(HW_YX + HW_ZX + HW_ZY) * NC * sizeof(short);
    size_t frag_b   = (8192 + 4096) * sizeof(short);
    size_t sort_b   = (size_t)N * 16;
    size_t meta_b   = ((size_t)NBINS * NB_SCAT + 2 * NBINS + 32) * sizeof(unsigned);
    size_t need     = planes_b + frag_b + sort_b + meta_b + 256;

    if (ws_size >= need) {
        unsigned short* tyx = (unsigned short*)d_ws;
        unsigned short* tzx = tyx + (size_t)HW_YX * NC;
        unsigned short* tzy = tzx + (size_t)HW_ZX * NC;
        short* w1a = (short*)(tzy + (size_t)HW_ZY * NC);
        short* w2a = w1a + 8192;
        float4* sorted = (float4*)(w2a + 4096);
        unsigned* bh       = (unsigned*)(sorted + N);
        unsigned* binTotal = bh + (size_t)NBINS * NB_SCAT;
        unsigned* binBase  = binTotal + NBINS;
        unsigned* gBase    = binBase + NBINS;

        int chunk = (int)(((size_t)N + NB_SCAT * 256 - 1) / ((size_t)NB_SCAT * 256)) * 256;

        kplane_prep_all<<<NB_PREP, 256, 0, stream>>>(pyx, pzx, pzy, w1, w2,
                                                     pts, N, chunk,
                                                     tyx, tzx, tzy,
                                                     w1a, w2a, bh);
        ksort_scanA<<<NBINS, 256, 0, stream>>>(bh, binTotal);
        ksort_scanB<<<1, 256, 0, stream>>>(binTotal, binBase, gBase, N);
        ksort_scatter<<<NB_SCAT, 256, 0, stream>>>(pts, N, chunk, bh, binBase, sorted);

        // per-z-group chunk capacity (uniform + 25% slack; while-loop covers rest)
        int cap = (N / NZB + N / (NZB * 4)) / 256 + 2;
        kplane_fused<<<16 * cap, 256, 0, stream>>>(sorted, gBase, cap,
                                                   tyx, tzx, tzy,
                                                   w1a, w2a, b1, b2, out);
    } else {
        int blocks = (N + 255) / 256;
        kplane_fused_direct<<<blocks, 256, 0, stream>>>(pts, pyx, pzx, pzy,
                                                        w1, b1, w2, b2, out, N);
    }
}

// Round 5
// 582.382 us; speedup vs baseline: 2.1073x; 1.0857x over previous
//
#include <hip/hip_runtime.h>
#include <hip/hip_fp16.h>
#include <hip/hip_bf16.h>

// Problem constants (from reference setup_inputs)
#define NC    32           // channels
#define NH1   256          // hidden dim
#define W_YX  727
#define H_YX  314
#define W_ZX  727
#define H_ZX  1300
#define W_ZY  314
#define H_ZY  1300
#define HW_YX (W_YX * H_YX)   // 228278
#define HW_ZX (W_ZX * H_ZX)   // 945100
#define HW_ZY (W_ZY * H_ZY)   // 408200

// spatial sort: 16 z-groups x 32 x-bins = 512 bins
#define NXB   32
#define NZB   16
#define NBINS (NXB * NZB)
#define NB_SCAT 512                      // scatter chunks (deterministic sort)

// merged prep-kernel block partition
#define NBW1  32                         // w1a: 8192 elems
#define NBW2  16                         // w2a: 4096 elems
#define NB_YX ((HW_YX + 255) / 256)      // 892
#define NB_ZX ((HW_ZX + 255) / 256)      // 3692
#define NB_ZY ((HW_ZY + 255) / 256)      // 1595
#define NB_PREP (NBW1 + NBW2 + NB_YX + NB_ZX + NB_ZY + NB_SCAT)

#define PSTRIDE 12         // dwords per point in parS  (12p%32: 2-way = free)
#define FSTRIDE 20         // dwords per point in featS (20p%32: 2-way, 16B-aligned)

typedef __attribute__((ext_vector_type(8))) short short8;   // 8 bf16 (4 VGPRs)
typedef __attribute__((ext_vector_type(4))) float f32x4;    // MFMA acc / io

// float -> bf16 (RNE), raw short (cold-path prep)
__device__ __forceinline__ short f2bf(float f) {
    unsigned u = __float_as_uint(f);
    unsigned r = u + 0x7fffu + ((u >> 16) & 1u);
    return (short)(r >> 16);
}
// pack two floats -> bf16 pair (RNE; v_cvt_pk_bf16_f32 on gfx950)
__device__ __forceinline__ unsigned pk2(float a, float b) {
    union { __hip_bfloat162 h; unsigned u; } c;
    c.h = __float22bfloat162_rn(make_float2(a, b));
    return c.u;
}

// spatial bin key: z-group (outer, 16) | x-bin (inner, 32).
// Localizes zx (bin patch), zy (z-slab), yx (x-slab) into per-XCD L2.
__device__ __forceinline__ int binkey(float px, float pz) {
    int xb = (int)((px + 1.0f) * 16.0f); xb = xb < 0 ? 0 : (xb > NXB - 1 ? NXB - 1 : xb);
    int zb = (int)((pz + 1.0f) * 8.0f);  zb = zb < 0 ? 0 : (zb > NZB - 1 ? NZB - 1 : zb);
    return zb * NXB + xb;
}

// ---------------------------------------------------------------------------
// Transpose body: (C=32, HW) fp32 -> (HW, C=32) bf16, 256 hw per block.
// ---------------------------------------------------------------------------
__device__ __forceinline__ void transpose_body(
    const float* __restrict__ src, unsigned short* __restrict__ dst,
    int HW, int hw0, int t)
{
    int c8 = t & 3;            // channel group (8 channels)
    int r  = t >> 2;           // 0..63: hw sub-tile
    int hwt = hw0 + r * 4;     // this thread's first hw

    if (hw0 + 256 <= HW) {
        f32x4 v[8];
#pragma unroll
        for (int cc = 0; cc < 8; ++cc) {
            int c = c8 * 8 + cc;
            v[cc] = *(const f32x4*)(src + (size_t)c * HW + hwt);
        }
#pragma unroll
        for (int k = 0; k < 4; ++k) {
            uint4 o;
            unsigned* ou = &o.x;
#pragma unroll
            for (int e = 0; e < 4; ++e)
                ou[e] = pk2(v[2 * e][k], v[2 * e + 1][k]);
            *(uint4*)(dst + (size_t)(hwt + k) * NC + c8 * 8) = o;
        }
    } else {
        for (int k = 0; k < 4; ++k) {
            int hw = hwt + k;
            if (hw < HW) {
                uint4 o;
                unsigned* ou = &o.x;
#pragma unroll
                for (int e = 0; e < 4; ++e) {
                    float a = src[(size_t)(c8 * 8 + 2 * e) * HW + hw];
                    float b = src[(size_t)(c8 * 8 + 2 * e + 1) * HW + hw];
                    ou[e] = pk2(a, b);
                }
                *(uint4*)(dst + (size_t)hw * NC + c8 * 8) = o;
            }
        }
    }
}

// ---------------------------------------------------------------------------
// ONE prep dispatch: w1a, w2a, 3 plane transposes, per-chunk histograms.
// Chunk h = points [h*chunk, (h+1)*chunk); bh[bin*NB_SCAT + h] = count.
// No global atomics anywhere.
// ---------------------------------------------------------------------------
__global__ __launch_bounds__(256) void kplane_prep_all(
    const float* __restrict__ pyx, const float* __restrict__ pzx,
    const float* __restrict__ pzy,
    const float* __restrict__ w1, const float* __restrict__ w2,
    const float* __restrict__ pts, int N, int chunk,
    unsigned short* __restrict__ tyx, unsigned short* __restrict__ tzx,
    unsigned short* __restrict__ tzy,
    short* __restrict__ w1a, short* __restrict__ w2a,
    unsigned* __restrict__ bh)
{
    __shared__ unsigned lh[NBINS];
    int b = blockIdx.x;
    int t = threadIdx.x;

    if (b < NBW1) {                                 // ---- w1a ----
        int idx = b * 256 + t;                      // 0..8191
        int j    = idx & 7;
        int lane = (idx >> 3) & 63;
        int nt   = idx >> 9;
        int ch  = (lane >> 4) * 8 + j;
        int hid = nt * 16 + (lane & 15);
        w1a[idx] = f2bf(w1[ch * NH1 + hid]);
        return;
    }
    b -= NBW1;
    if (b < NBW2) {                                 // ---- w2a ----
        int idx = b * 256 + t;                      // 0..4095
        int j    = idx & 7;
        int lane = (idx >> 3) & 63;
        int kk   = idx >> 9;
        int o    = lane & 15;
        int quad = lane >> 4;
        int hid  = (2 * kk + (j >> 2)) * 16 + quad * 4 + (j & 3);
        float v  = (o < 4) ? w2[hid * 4 + o] : 0.0f;
        w2a[idx] = f2bf(v);
        return;
    }
    b -= NBW2;
    if (b < NB_YX + NB_ZX + NB_ZY) {                // ---- transposes ----
        const float* src; unsigned short* dst; int HW;
        if (b < NB_YX)              { src = pyx; dst = tyx; HW = HW_YX; }
        else if (b < NB_YX + NB_ZX) { b -= NB_YX; src = pzx; dst = tzx; HW = HW_ZX; }
        else                        { b -= NB_YX + NB_ZX; src = pzy; dst = tzy; HW = HW_ZY; }
        transpose_body(src, dst, HW, b * 256, t);
        return;
    }
    b -= NB_YX + NB_ZX + NB_ZY;                     // ---- chunk histogram ----
    lh[t] = 0; lh[t + 256] = 0;
    __syncthreads();
    long i0 = (long)b * chunk;
    for (int k = 0; k < chunk; k += 256) {
        long i = i0 + k + t;
        if (i < N) {
            float px = pts[i * 3 + 0];
            float pz = pts[i * 3 + 2];
            atomicAdd(&lh[binkey(px, pz)], 1u);     // LDS atomic only
        }
    }
    __syncthreads();
    bh[(size_t)t * NB_SCAT + b]         = lh[t];
    bh[(size_t)(t + 256) * NB_SCAT + b] = lh[t + 256];
}

// ---------------------------------------------------------------------------
// Scan A: per bin, exclusive scan over the NB_SCAT chunk counts (in place);
// binTotal[bin] = sum. One block per bin.
// ---------------------------------------------------------------------------
__global__ __launch_bounds__(256) void ksort_scanA(
    unsigned* __restrict__ bh, unsigned* __restrict__ binTotal)
{
    __shared__ unsigned s[NB_SCAT];
    int b = blockIdx.x, t = threadIdx.x;
    s[t]       = bh[(size_t)b * NB_SCAT + t];
    s[t + 256] = bh[(size_t)b * NB_SCAT + 256 + t];
    __syncthreads();
    if (t == 0) {
        unsigned a = 0;
        for (int k = 0; k < NB_SCAT; ++k) { unsigned v = s[k]; s[k] = a; a += v; }
        binTotal[b] = a;
    }
    __syncthreads();
    bh[(size_t)b * NB_SCAT + t]       = s[t];
    bh[(size_t)b * NB_SCAT + 256 + t] = s[t + 256];
}

// ---------------------------------------------------------------------------
// Scan B: exclusive scan over 512 bin totals -> binBase; z-group ranges.
// ---------------------------------------------------------------------------
__global__ __launch_bounds__(256) void ksort_scanB(
    const unsigned* __restrict__ binTotal, unsigned* __restrict__ binBase,
    unsigned* __restrict__ gBase, int N)
{
    __shared__ unsigned s[NBINS];
    int t = threadIdx.x;
    s[t] = binTotal[t]; s[t + 256] = binTotal[t + 256];
    __syncthreads();
    if (t == 0) {
        unsigned a = 0;
        for (int k = 0; k < NBINS; ++k) { unsigned v = s[k]; s[k] = a; a += v; }
    }
    __syncthreads();
    binBase[t] = s[t]; binBase[t + 256] = s[t + 256];
    if (t < NZB) gBase[t] = s[t * NXB];
    if (t == 0)  gBase[NZB] = (unsigned)N;
}

// ---------------------------------------------------------------------------
// Scatter: block h re-reads its chunk, ranks points per bin via LDS counters,
// writes to exact slot binBase[key] + bh[key][h] + rank. Zero global atomics;
// per-(block,bin) output runs are contiguous -> low write amplification.
// ---------------------------------------------------------------------------
__global__ __launch_bounds__(256) void ksort_scatter(
    const float* __restrict__ pts, int N, int chunk,
    const unsigned* __restrict__ bh, const unsigned* __restrict__ binBase,
    float4* __restrict__ sp)
{
    __shared__ unsigned cnt[NBINS];
    __shared__ unsigned baseS[NBINS];
    int h = blockIdx.x, t = threadIdx.x;
    cnt[t] = 0; cnt[t + 256] = 0;
    baseS[t]       = binBase[t]       + bh[(size_t)t * NB_SCAT + h];
    baseS[t + 256] = binBase[t + 256] + bh[(size_t)(t + 256) * NB_SCAT + h];
    __syncthreads();
    long i0 = (long)h * chunk;
    for (int k = 0; k < chunk; k += 256) {
        long i = i0 + k + t;
        if (i < N) {
            float px = pts[i * 3 + 0];
            float py = pts[i * 3 + 1];
            float pz = pts[i * 3 + 2];
            int key = binkey(px, pz);
            unsigned rank = atomicAdd(&cnt[key], 1u);   // LDS atomic only
            float4 o; o.x = px; o.y = py; o.z = pz;
            o.w = __uint_as_float((unsigned)i);
            sp[baseS[key] + rank] = o;
        }
    }
}

// ---------------------------------------------------------------------------
// Bilinear setup: byte offsets of the two y-rows at x0 (x1 = +64B implicit;
// at the x-clamp edge wx==0 so the x1 half is weighted to zero).
// ---------------------------------------------------------------------------
__device__ __forceinline__ void bilin3(
    float gx, float gy, int W, int H,
    unsigned& o0, unsigned& o1, float& wx, float& wy)
{
    float ix  = (gx + 1.0f) * 0.5f * (float)(W - 1);
    float iy  = (gy + 1.0f) * 0.5f * (float)(H - 1);
    float x0f = floorf(ix), y0f = floorf(iy);
    wx = ix - x0f; wy = iy - y0f;
    int x0 = (int)x0f; x0 = x0 < 0 ? 0 : (x0 > W - 1 ? W - 1 : x0);
    int y0 = (int)y0f; y0 = y0 < 0 ? 0 : (y0 > H - 1 ? H - 1 : y0);
    int y1 = y0 + 1; if (y1 > H - 1) y1 = H - 1;
    o0 = (unsigned)(y0 * W + x0) * 64u;
    o1 = (unsigned)(y1 * W + x0) * 64u;
}

// Bilinear-combine 4 corner chunks (8 channels) fully in-lane.
template <bool FIRST>
__device__ __forceinline__ void corner4(
    const uint4& A, const uint4& B, const uint4& C, const uint4& D,
    float wx, float wy, float F[8])
{
    float w00 = (1.0f - wx) * (1.0f - wy);
    float w01 = wx * (1.0f - wy);
    float w10 = (1.0f - wx) * wy;
    float w11 = wx * wy;
    const unsigned* ua = &A.x; const unsigned* ub = &B.x;
    const unsigned* uc = &C.x; const unsigned* ud = &D.x;
#pragma unroll
    for (int e = 0; e < 4; ++e) {
        float a0 = __uint_as_float(ua[e] << 16);
        float a1 = __uint_as_float(ua[e] & 0xffff0000u);
        float b0 = __uint_as_float(ub[e] << 16);
        float b1 = __uint_as_float(ub[e] & 0xffff0000u);
        float c0 = __uint_as_float(uc[e] << 16);
        float c1 = __uint_as_float(uc[e] & 0xffff0000u);
        float d0 = __uint_as_float(ud[e] << 16);
        float d1 = __uint_as_float(ud[e] & 0xffff0000u);
        float v0 = w00 * a0; v0 = fmaf(w01, b0, v0);
        v0 = fmaf(w10, c0, v0); v0 = fmaf(w11, d0, v0);
        float v1 = w00 * a1; v1 = fmaf(w01, b1, v1);
        v1 = fmaf(w10, c1, v1); v1 = fmaf(w11, d1, v1);
        if (FIRST) { F[2 * e] = v0; F[2 * e + 1] = v1; }
        else       { F[2 * e] *= v0; F[2 * e + 1] *= v1; }
    }
}

// ---------------------------------------------------------------------------
// Fused kernel over SORTED points, XCD-pinned, ONE 256-pt chunk per block
// (no loop-carried state -> low VGPR -> 4 blocks/CU).
// block: xcd = blockIdx%8 -> z-groups {xcd, xcd+8}; j = chunk index in group.
// ---------------------------------------------------------------------------
__global__ __launch_bounds__(256, 4) void kplane_fused(
    const float4* __restrict__ sp, const unsigned* __restrict__ gBase, int cap,
    const unsigned short* __restrict__ tyx,
    const unsigned short* __restrict__ tzx,
    const unsigned short* __restrict__ tzy,
    const short* __restrict__ w1a, const short* __restrict__ w2a,
    const float* __restrict__ b1, const float* __restrict__ b2,
    float* __restrict__ out)
{
    __shared__ unsigned parS[256 * PSTRIDE];    // 12 KB
    __shared__ unsigned featS[256 * FSTRIDE];   // 20 KB
    __shared__ unsigned idxS[256];              // 1 KB

    int t = threadIdx.x;
    int bxcd = blockIdx.x & 7;
    int i    = blockIdx.x >> 3;
    int g    = bxcd + 8 * (i >= cap);
    int j    = (i >= cap) ? i - cap : i;
    unsigned gb = gBase[g], ge = gBase[g + 1];
    unsigned start = gb + (unsigned)j * 256u;
    if (start >= ge) return;                    // block-uniform early exit
    int npts = (int)(ge - start); if (npts > 256) npts = 256;

    // ---- phase 0: bilinear params for point `t` ---------------------------
    {
        uint4 P0 = {0,0,0,0}, P1 = {0,0,0,0}, P2 = {0,0,0,0};
        unsigned oid = 0xFFFFFFFFu;
        if (t < npts) {
            float4 p = sp[start + t];
            oid = __float_as_uint(p.w);
            unsigned a0, a1, c0, c1, d0, d1;
            float awx, awy, cwx, cwy, dwx, dwy;
            bilin3(p.x, p.y, W_YX, H_YX, a0, a1, awx, awy);
            bilin3(p.x, p.z, W_ZX, H_ZX, c0, c1, cwx, cwy);
            bilin3(p.y, p.z, W_ZY, H_ZY, d0, d1, dwx, dwy);
            P0 = {a0, a1, c0, c1};
            P1 = {d0, d1, __float_as_uint(awx), __float_as_uint(awy)};
            P2 = {__float_as_uint(cwx), __float_as_uint(cwy),
                  __float_as_uint(dwx), __float_as_uint(dwy)};
        }
        uint4* P = (uint4*)&parS[t * PSTRIDE];
        P[0] = P0; P[1] = P1; P[2] = P2;
        idxS[t] = oid;
    }
    __syncthreads();

    // ---- phase 1: gather, 4 lanes/point -----------------------------------
    {
        int q = t >> 2, jj = t & 3;
        int jx16 = jj * 16;
        const char* Byx = (const char*)tyx;
        const char* Bzx = (const char*)tzx;
        const char* Bzy = (const char*)tzy;
#pragma unroll
        for (int r = 0; r < 4; ++r) {
            int p = r * 64 + q;
            const uint4* P = (const uint4*)&parS[p * PSTRIDE];
            uint4 P0 = P[0], P1 = P[1], P2 = P[2];
            float awx = __uint_as_float(P1.z), awy = __uint_as_float(P1.w);
            float cwx = __uint_as_float(P2.x), cwy = __uint_as_float(P2.y);
            float dwx = __uint_as_float(P2.z), dwy = __uint_as_float(P2.w);

            uint4 La = *(const uint4*)(Byx + P0.x + jx16);
            uint4 Lb = *(const uint4*)(Byx + P0.x + 64 + jx16);
            uint4 Lc = *(const uint4*)(Byx + P0.y + jx16);
            uint4 Ld = *(const uint4*)(Byx + P0.y + 64 + jx16);
            uint4 Ma = *(const uint4*)(Bzx + P0.z + jx16);
            uint4 Mb = *(const uint4*)(Bzx + P0.z + 64 + jx16);
            uint4 Mc = *(const uint4*)(Bzx + P0.w + jx16);
            uint4 Md = *(const uint4*)(Bzx + P0.w + 64 + jx16);
            uint4 Na = *(const uint4*)(Bzy + P1.x + jx16);
            uint4 Nb = *(const uint4*)(Bzy + P1.x + 64 + jx16);
            uint4 Nc = *(const uint4*)(Bzy + P1.y + jx16);
            uint4 Nd = *(const uint4*)(Bzy + P1.y + 64 + jx16);

            float F[8];
            corner4<true >(La, Lb, Lc, Ld, awx, awy, F);
            corner4<false>(Ma, Mb, Mc, Md, cwx, cwy, F);
            corner4<false>(Na, Nb, Nc, Nd, dwx, dwy, F);

            uint4 o;
            o.x = pk2(F[0], F[1]); o.y = pk2(F[2], F[3]);
            o.z = pk2(F[4], F[5]); o.w = pk2(F[6], F[7]);
            *(uint4*)&featS[p * FSTRIDE + jj * 4] = o;
        }
    }
    __syncthreads();

    // ---- phase 2: MFMA1 -> relu/pack -> MFMA2 -----------------------------
    {
        int w = t >> 6, lane = t & 63;
        int quad = lane >> 4, l15 = lane & 15;
        const short8* W1A = (const short8*)w1a;
        const short8* W2A = (const short8*)w2a;
        const float4* B1v = (const float4*)b1;
        float b20 = b2[0], b21 = b2[1], b22 = b2[2], b23 = b2[3];

#pragma unroll
        for (int mt = 0; mt < 4; ++mt) {
            int pt = w * 64 + mt * 16 + l15;
            union { uint4 v; short8 s; } bf;
            bf.v = *(const uint4*)&featS[pt * FSTRIDE + quad * 4];

            f32x4 acc = {0.f, 0.f, 0.f, 0.f};
#pragma unroll
            for (int kk = 0; kk < 8; ++kk) {
                float4 be = B1v[(2 * kk) * 4 + quad];
                float4 bo = B1v[(2 * kk + 1) * 4 + quad];
                f32x4 ze = {be.x, be.y, be.z, be.w};
                f32x4 zo = {bo.x, bo.y, bo.z, bo.w};
                ze = __builtin_amdgcn_mfma_f32_16x16x32_bf16(
                         W1A[(2 * kk) * 64 + lane], bf.s, ze, 0, 0, 0);
                zo = __builtin_amdgcn_mfma_f32_16x16x32_bf16(
                         W1A[(2 * kk + 1) * 64 + lane], bf.s, zo, 0, 0, 0);
                union { unsigned u[4]; short8 s; } hb;
                hb.u[0] = pk2(fmaxf(ze[0], 0.f), fmaxf(ze[1], 0.f));
                hb.u[1] = pk2(fmaxf(ze[2], 0.f), fmaxf(ze[3], 0.f));
                hb.u[2] = pk2(fmaxf(zo[0], 0.f), fmaxf(zo[1], 0.f));
                hb.u[3] = pk2(fmaxf(zo[2], 0.f), fmaxf(zo[3], 0.f));
                acc = __builtin_amdgcn_mfma_f32_16x16x32_bf16(
                          W2A[kk * 64 + lane], hb.s, acc, 0, 0, 0);
            }
            unsigned orig = idxS[pt];
            if (quad == 0 && orig != 0xFFFFFFFFu) {
                f32x4 o = {acc[0] + b20, acc[1] + b21, acc[2] + b22, acc[3] + b23};
                *((f32x4*)out + orig) = o;
            }
        }
    }
}

// ---------------------------------------------------------------------------
// Fallback path (ws too small): direct (C,H,W) gather, VALU MLP.
// ---------------------------------------------------------------------------
__device__ __forceinline__ void bilin_full(
    float gx, float gy, int W, int H,
    int& o00, int& o01, int& o10, int& o11,
    float& w00, float& w01, float& w10, float& w11)
{
    float ix  = (gx + 1.0f) * 0.5f * (float)(W - 1);
    float iy  = (gy + 1.0f) * 0.5f * (float)(H - 1);
    float x0f = floorf(ix), y0f = floorf(iy);
    float wx  = ix - x0f,   wy  = iy - y0f;
    int x0 = (int)x0f; x0 = x0 < 0 ? 0 : (x0 > W - 1 ? W - 1 : x0);
    int y0 = (int)y0f; y0 = y0 < 0 ? 0 : (y0 > H - 1 ? H - 1 : y0);
    int x1 = x0 + 1; if (x1 > W - 1) x1 = W - 1;
    int y1 = y0 + 1; if (y1 > H - 1) y1 = H - 1;
    o00 = y0 * W + x0; o01 = y0 * W + x1;
    o10 = y1 * W + x0; o11 = y1 * W + x1;
    w00 = (1.0f - wx) * (1.0f - wy);
    w01 = wx * (1.0f - wy);
    w10 = (1.0f - wx) * wy;
    w11 = wx * wy;
}

__global__ __launch_bounds__(256) void kplane_fused_direct(
    const float* __restrict__ pts,
    const float* __restrict__ pyx, const float* __restrict__ pzx,
    const float* __restrict__ pzy,
    const float* __restrict__ w1, const float* __restrict__ b1,
    const float* __restrict__ w2, const float* __restrict__ b2,
    float* __restrict__ out, int N)
{
    int i = blockIdx.x * blockDim.x + threadIdx.x;
    if (i >= N) return;
    float px = pts[(size_t)i * 3 + 0];
    float py = pts[(size_t)i * 3 + 1];
    float pz = pts[(size_t)i * 3 + 2];

    int a00, a01, a10, a11; float aw00, aw01, aw10, aw11;
    int c00, c01, c10, c11; float cw00, cw01, cw10, cw11;
    int d00, d01, d10, d11; float dw00, dw01, dw10, dw11;
    bilin_full(px, py, W_YX, H_YX, a00, a01, a10, a11, aw00, aw01, aw10, aw11);
    bilin_full(px, pz, W_ZX, H_ZX, c00, c01, c10, c11, cw00, cw01, cw10, cw11);
    bilin_full(py, pz, W_ZY, H_ZY, d00, d01, d10, d11, dw00, dw01, dw10, dw11);

    float feat[NC];
#pragma unroll 4
    for (int c = 0; c < NC; ++c) {
        const float* byx = pyx + (size_t)c * HW_YX;
        const float* bzx = pzx + (size_t)c * HW_ZX;
        const float* bzy = pzy + (size_t)c * HW_ZY;
        float fyx = aw00 * byx[a00] + aw01 * byx[a01] + aw10 * byx[a10] + aw11 * byx[a11];
        float fzx = cw00 * bzx[c00] + cw01 * bzx[c01] + cw10 * bzx[c10] + cw11 * bzx[c11];
        float fzy = dw00 * bzy[d00] + dw01 * bzy[d10 - d10 + d01] + dw10 * bzy[d10] + dw11 * bzy[d11];
        feat[c] = fyx * fzx * fzy;
    }
    float o0 = b2[0], o1 = b2[1], o2 = b2[2], o3 = b2[3];
#pragma unroll 4
    for (int k = 0; k < NH1; ++k) {
        float hk = b1[k];
#pragma unroll
        for (int c = 0; c < NC; ++c)
            hk = fmaf(feat[c], w1[c * NH1 + k], hk);
        hk = fmaxf(hk, 0.0f);
        o0 = fmaf(hk, w2[k * 4 + 0], o0);
        o1 = fmaf(hk, w2[k * 4 + 1], o1);
        o2 = fmaf(hk, w2[k * 4 + 2], o2);
        o3 = fmaf(hk, w2[k * 4 + 3], o3);
    }
    float4 o; o.x = o0; o.y = o1; o.z = o2; o.w = o3;
    reinterpret_cast<float4*>(out)[i] = o;
}

// ---------------------------------------------------------------------------
extern "C" void kernel_launch(void* const* d_in, const int* in_sizes, int n_in,
                              void* d_out, int out_size, void* d_ws, size_t ws_size,
                              hipStream_t stream)
{
    const float* pts = (const float*)d_in[0];
    const float* pyx = (const float*)d_in[1];
    const float* pzx = (const float*)d_in[2];
    const float* pzy = (const float*)d_in[3];
    const float* w1  = (const float*)d_in[4];
    const float* b1  = (const float*)d_in[5];
    const float* w2  = (const float*)d_in[6];
    const float* b2  = (const float*)d_in[7];
    float* out = (float*)d_out;

    int N = in_sizes[0] / 3;

    size_t planes_b = (size_t)(HW_YX + HW_ZX + HW_ZY) * NC * sizeof(short);
    size_t frag_b   = (8192 + 4096) * sizeof(short);
    size_t sort_b   = (size_t)N * 16;
    size_t meta_b   = ((size_t)NBINS * NB_SCAT + 2 * NBINS + 32) * sizeof(unsigned);
    size_t need     = planes_b + frag_b + sort_b + meta_b + 256;

    if (ws_size >= need) {
        unsigned short* tyx = (unsigned short*)d_ws;
        unsigned short* tzx = tyx + (size_t)HW_YX * NC;
        unsigned short* tzy = tzx + (size_t)HW_ZX * NC;
        short* w1a = (short*)(tzy + (size_t)HW_ZY * NC);
        short* w2a = w1a + 8192;
        float4* sorted = (float4*)(w2a + 4096);
        unsigned* bh       = (unsigned*)(sorted + N);
        unsigned* binTotal = bh + (size_t)NBINS * NB_SCAT;
        unsigned* binBase  = binTotal + NBINS;
        unsigned* gBase    = binBase + NBINS;

        int chunk = (int)(((size_t)N + NB_SCAT * 256 - 1) / ((size_t)NB_SCAT * 256)) * 256;

        kplane_prep_all<<<NB_PREP, 256, 0, stream>>>(pyx, pzx, pzy, w1, w2,
                                                     pts, N, chunk,
                                                     tyx, tzx, tzy,
                                                     w1a, w2a, bh);
        ksort_scanA<<<NBINS, 256, 0, stream>>>(bh, binTotal);
        ksort_scanB<<<1, 256, 0, stream>>>(binTotal, binBase, gBase, N);
        ksort_scatter<<<NB_SCAT, 256, 0, stream>>>(pts, N, chunk, bh, binBase, sorted);

        // per-z-group chunk capacity (uniform + 25% slack; early-exit covers rest)
        int cap = (N / NZB + N / (NZB * 4)) / 256 + 2;
        kplane_fused<<<16 * cap, 256, 0, stream>>>(sorted, gBase, cap,
                                                   tyx, tzx, tzy,
                                                   w1a, w2a, b1, b2, out);
    } else {
        int blocks = (N + 255) / 256;
        kplane_fused_direct<<<blocks, 256, 0, stream>>>(pts, pyx, pzx, pzy,
                                                        w1, b1, w2, b2, out, N);
    }
}